// Round 4
// baseline (162.818 us; speedup 1.0000x reference)
//
#include <hip/hip_runtime.h>
#include <hip/hip_bf16.h>

#define N_NODES 16000
#define N_EDGES 80000
#define N_GRAPHS 64
#define NBASIS 10

#define SILU_NORM 1.679177f
#define SMOOTH_C (1.14136f * 7.38905609893065f)   // 1.14136*e^2
#define SQRT10 3.16227766016838f
#define INV_SQRT10 0.316227766016838f
#define SQRT3 1.7320508075688772f
#define QK_NORM 0.04419417382415922f              // 1/sqrt(2*16*16)
#define SCALE_B 0.02209708691207961f              // (1/8)*(1/sqrt(32))
#define RSTEP (11.0f / 6.0f)
#define STEP (6.0f / 11.0f)
#define BC (SMOOTH_C * SQRT10)
#define NACC 256

__device__ __forceinline__ float sus_f(float x) {
    return x > 0.0f ? __expf(-__fdividef(1.0f, x)) : 0.0f;
}

__device__ __forceinline__ void basis_regs(float len, float* b) {
#pragma unroll
    for (int i = 0; i < NBASIS; ++i) {
        float d = (len - STEP * (float)(i + 1)) * RSTEP;
        float pd = 1.0f + d, md = 1.0f - d;
        float e = __expf(-(__fdividef(1.0f, pd) + __fdividef(1.0f, md)));
        b[i] = (pd > 0.0f && md > 0.0f) ? BC * e : 0.0f;
    }
}

__device__ __forceinline__ float silu_n(float s) {
    return __fdividef(SILU_NORM * s, 1.0f + __expf(-s));
}

// Coalesced table builder: 96 blocks = 3 tables x 32 m-rows. Each thread owns
// a fixed w column (tid&15), W2 row column cached in registers, z_table in LDS.
__global__ void build_tables(const float* __restrict__ z_table,
                             const float* __restrict__ mol_table,
                             const float* __restrict__ W2k,
                             const float* __restrict__ W2v,
                             float* __restrict__ BkT, float* __restrict__ Bv0T,
                             float* __restrict__ Bv1T) {
    __shared__ float zt[4800];
    __shared__ float mt[32];
    int b = blockIdx.x;
    int t = b >> 5;          // 0=k, 1=v0, 2=v1
    int m = b & 31;
    int tid = threadIdx.x;   // 256
    int w = tid & 15;
    for (int i = tid; i < 4800; i += 256) zt[i] = z_table[i];
    if (tid < 32) mt[tid] = mol_table[tid];
    const float* src = (t == 0) ? (W2k + m * 2048)
                     : (t == 1) ? (W2v + m * 2048)
                                : (W2v + m * 2048 + 1024);
    float w2c[64];
#pragma unroll
    for (int u = 0; u < 64; ++u) w2c[u] = src[u * 16 + w];   // coalesced per 16 lanes
    __syncthreads();
    float* dstT = (t == 0) ? BkT : (t == 1) ? Bv0T : Bv1T;
    for (int o = tid; o < 200 * 16; o += 256) {
        int combo = o >> 4;          // w == o&15 == tid&15 (stride 256 preserves)
        int elem = combo >> 1, mol = combo & 1;
        const float* f = &zt[elem * 48];
        float s = 0.0f;
#pragma unroll
        for (int u = 0; u < 48; ++u) s += f[u] * w2c[u];
        const float* mm = &mt[mol * 16];
#pragma unroll
        for (int u = 0; u < 16; ++u) s += mm[u] * w2c[48 + u];
        dstT[combo * 512 + w * 32 + m] = s * SCALE_B;
    }
}

// qa[combo][w] = QK_NORM/8 * sum_u feat[u] * (Wq@Wa)[u][w]
__global__ void build_qa(const float* __restrict__ z_table,
                         const float* __restrict__ mol_table,
                         const float* __restrict__ Wq,
                         const float* __restrict__ Wa,
                         float* __restrict__ qa) {
    __shared__ float wqa[64 * 16];
    __shared__ float zt[4800];
    __shared__ float mt[32];
    int tid = threadIdx.x;   // 1024
    {
        int u = tid >> 4, w = tid & 15;
        float s = 0.0f;
#pragma unroll
        for (int v = 0; v < 16; ++v) s += Wq[u * 16 + v] * Wa[v * 16 + w];
        wqa[u * 16 + w] = s;
    }
    for (int i = tid; i < 4800; i += 1024) zt[i] = z_table[i];
    if (tid < 32) mt[tid] = mol_table[tid];
    __syncthreads();
    for (int o = tid; o < 200 * 16; o += 1024) {
        int combo = o >> 4, w = o & 15;
        int elem = combo >> 1, mol = combo & 1;
        float s = 0.0f;
#pragma unroll
        for (int u = 0; u < 48; ++u) s += zt[elem * 48 + u] * wqa[u * 16 + w];
#pragma unroll
        for (int u = 0; u < 16; ++u) s += mt[mol * 16 + u] * wqa[(48 + u) * 16 + w];
        qa[combo * 16 + w] = s * 0.125f * QK_NORM;
    }
}

// Edge pass: ALL per-edge compute. 16 lanes/edge. Stores unnormalized
// (v0,s1v) float2 per (edge,w), (sh*sqrt3, expv) float4, packed dst|g.
__global__ void edge_kernel(const float* __restrict__ pos,
                            const int* __restrict__ xarr, const int* __restrict__ molid,
                            const int* __restrict__ esrc, const int* __restrict__ edst,
                            const int* __restrict__ batch,
                            const float* __restrict__ W1k, const float* __restrict__ W1v,
                            const float* __restrict__ BkT, const float* __restrict__ Bv0T,
                            const float* __restrict__ Bv1T, const float* __restrict__ qa,
                            float4* __restrict__ geomexp, int* __restrict__ pkbuf,
                            float2* __restrict__ vsbuf, float* __restrict__ zbuf) {
    __shared__ float hk[16][36];
    __shared__ float hv[16][36];
    int tid = threadIdx.x;
    int lane = tid & 15;
    int grp = tid >> 4;
    int e = blockIdx.x * 16 + grp;           // 80000 = 5000*16
    int src = esrc[e], dst = edst[e];
    float vx = pos[src * 3 + 0] - pos[dst * 3 + 0];
    float vy = pos[src * 3 + 1] - pos[dst * 3 + 1];
    float vz = pos[src * 3 + 2] - pos[dst * 3 + 2];
    float len = sqrtf(vx * vx + vy * vy + vz * vz);

    float b[NBASIS];
    basis_regs(len, b);

    float sk0 = 0.0f, sk1 = 0.0f, sv0 = 0.0f, sv1 = 0.0f;
#pragma unroll
    for (int i = 0; i < NBASIS; ++i) {
        float bi = b[i];
        sk0 += bi * W1k[i * 32 + lane];
        sk1 += bi * W1k[i * 32 + lane + 16];
        sv0 += bi * W1v[i * 32 + lane];
        sv1 += bi * W1v[i * 32 + lane + 16];
    }
    hk[grp][lane]      = silu_n(sk0 * INV_SQRT10);
    hk[grp][lane + 16] = silu_n(sk1 * INV_SQRT10);
    hv[grp][lane]      = silu_n(sv0 * INV_SQRT10);
    hv[grp][lane + 16] = silu_n(sv1 * INV_SQRT10);

    int cs = xarr[src] * 2 + molid[src];
    int cd = xarr[dst] * 2 + molid[dst];
    int g  = batch[dst];

    const float4* hpk = (const float4*)&hk[grp][0];
    const float4* hpv = (const float4*)&hv[grp][0];
    const float4* bk = (const float4*)(BkT  + cs * 512 + lane * 32);
    const float4* b0 = (const float4*)(Bv0T + cs * 512 + lane * 32);
    const float4* b1 = (const float4*)(Bv1T + cs * 512 + lane * 32);
    float k0 = 0.0f, v0 = 0.0f, s1v = 0.0f;
#pragma unroll
    for (int mq = 0; mq < 8; ++mq) {
        float4 h4 = hpk[mq];
        float4 a  = bk[mq];
        k0 += h4.x * a.x + h4.y * a.y + h4.z * a.z + h4.w * a.w;
        float4 g4 = hpv[mq];
        float4 a0 = b0[mq];
        float4 a1 = b1[mq];
        v0  += g4.x * a0.x + g4.y * a0.y + g4.z * a0.z + g4.w * a0.w;
        s1v += g4.x * a1.x + g4.y * a1.y + g4.z * a1.z + g4.w * a1.w;
    }
    float p = qa[cd * 16 + lane] * k0;
#pragma unroll
    for (int off = 1; off < 16; off <<= 1) p += __shfl_xor(p, off, 16);

    vsbuf[e * 16 + lane] = make_float2(v0, s1v);
    if (lane == 0) {
        float cutoff = sus_f(10.0f * (1.0f - len * (1.0f / 6.0f)));
        float ev = cutoff * __expf(p);
        atomicAdd(&zbuf[dst], ev);
        float il = SQRT3 / len;
        geomexp[e] = make_float4(vx * il, vy * il, vz * il, ev);
        pkbuf[e] = dst | (g << 14);
    }
}

// Accumulate: trivial stream — att = sqrt(ev/z), 4 LDS atomics per lane.
__global__ void __launch_bounds__(1024)
acc_kernel(const float4* __restrict__ geomexp, const int* __restrict__ pkbuf,
           const float2* __restrict__ vsbuf, const float* __restrict__ zbuf,
           float* __restrict__ partial) {
    __shared__ float acc[N_GRAPHS * 68];
    int tid = threadIdx.x;
    int lane = tid & 15;
    int grp = tid >> 4;      // 0..63
    for (int i = tid; i < N_GRAPHS * 68; i += 1024) acc[i] = 0.0f;
    __syncthreads();
    int gid = blockIdx.x * 64 + grp;
    for (int e = gid; e < N_EDGES; e += NACC * 64) {
        float4 ge = geomexp[e];
        int pk = pkbuf[e];
        float2 vs = vsbuf[e * 16 + lane];
        int dst = pk & 16383;
        int g = pk >> 14;
        float z = zbuf[dst];
        if (z == 0.0f) z = 1.0f;
        float att = sqrtf(__fdividef(ge.w, z));
        float v0 = vs.x * att;
        float s1v = vs.y * att;
        float* row = &acc[g * 68];
        atomicAdd(&row[lane], v0);
        atomicAdd(&row[16 + lane * 3 + 0], s1v * ge.x);
        atomicAdd(&row[16 + lane * 3 + 1], s1v * ge.y);
        atomicAdd(&row[16 + lane * 3 + 2], s1v * ge.z);
    }
    __syncthreads();
    for (int i = tid; i < N_GRAPHS * 64; i += 1024)
        partial[blockIdx.x * (N_GRAPHS * 64) + i] = acc[(i >> 6) * 68 + (i & 63)];
}

__global__ void reduce_kernel(const float* __restrict__ partial,
                              const int* __restrict__ batch,
                              float* __restrict__ out) {
    __shared__ float red[4][64];
    int g = blockIdx.x;
    int c = threadIdx.x & 63;
    int q = threadIdx.x >> 6;
    float s = 0.0f;
    for (int bb = q; bb < NACC; bb += 4) s += partial[bb * (N_GRAPHS * 64) + g * 64 + c];
    red[q][c] = s;
    __syncthreads();
    if (q == 0) {
        float tot = red[0][c] + red[1][c] + red[2][c] + red[3][c];
        int lo = 0, hi = N_NODES;
        while (lo < hi) { int m = (lo + hi) >> 1; if (batch[m] < g) lo = m + 1; else hi = m; }
        int st = lo;
        lo = st; hi = N_NODES;
        while (lo < hi) { int m = (lo + hi) >> 1; if (batch[m] <= g) lo = m + 1; else hi = m; }
        int cnt = lo - st;
        if (cnt < 1) cnt = 1;
        out[g * 64 + c] = tot / (float)cnt;
    }
}

extern "C" void kernel_launch(void* const* d_in, const int* in_sizes, int n_in,
                              void* d_out, int out_size, void* d_ws, size_t ws_size,
                              hipStream_t stream) {
    const float* pos       = (const float*)d_in[0];
    const float* z_table   = (const float*)d_in[1];
    const float* mol_table = (const float*)d_in[2];
    const float* Wq        = (const float*)d_in[3];
    const float* W1k       = (const float*)d_in[4];
    const float* W2k       = (const float*)d_in[5];
    const float* W1v       = (const float*)d_in[6];
    const float* W2v       = (const float*)d_in[7];
    const float* Wa        = (const float*)d_in[8];
    // d_in[9] = Wb: unused (q1 == 0 in the reference)
    const int* x     = (const int*)d_in[10];
    const int* molid = (const int*)d_in[11];
    const int* esrc  = (const int*)d_in[12];
    const int* edst  = (const int*)d_in[13];
    const int* batch = (const int*)d_in[14];
    float* out = (float*)d_out;

    float* ws = (float*)d_ws;
    float*  BkT     = ws;                          // 102400
    float*  Bv0T    = BkT  + 200 * 512;            // 102400
    float*  Bv1T    = Bv0T + 200 * 512;            // 102400
    float*  qa      = Bv1T + 200 * 512;            // 3200
    float*  zbuf    = qa   + 200 * 16;             // 16000
    float4* geomexp = (float4*)(zbuf + N_NODES);   // 80000 f4  (offset 326400, 16B aligned)
    int*    pkbuf   = (int*)(geomexp + N_EDGES);   // 80000
    float2* vsbuf   = (float2*)(pkbuf + N_EDGES);  // 80000*16 f2 (8B aligned)
    float*  partial = (float*)(vsbuf + N_EDGES * 16); // NACC*4096

    hipMemsetAsync(zbuf, 0, N_NODES * sizeof(float), stream);

    build_tables<<<96, 256, 0, stream>>>(z_table, mol_table, W2k, W2v, BkT, Bv0T, Bv1T);
    build_qa<<<1, 1024, 0, stream>>>(z_table, mol_table, Wq, Wa, qa);
    edge_kernel<<<N_EDGES / 16, 256, 0, stream>>>(pos, x, molid, esrc, edst, batch,
                                                  W1k, W1v, BkT, Bv0T, Bv1T, qa,
                                                  geomexp, pkbuf, vsbuf, zbuf);
    acc_kernel<<<NACC, 1024, 0, stream>>>(geomexp, pkbuf, vsbuf, zbuf, partial);
    reduce_kernel<<<N_GRAPHS, 256, 0, stream>>>(partial, batch, out);
}